// Round 1
// baseline (1337.157 us; speedup 1.0000x reference)
//
#include <hip/hip_runtime.h>
#include <hip/hip_bf16.h>

// out[b,t,v] = sum_d x[b,t,d,v]*w[d] + bias
// x: (B=2, T=512, D=8, V=32000) fp32, contiguous in v.
// Memory-bound: 1.049 GB read + 131 MB write -> ~187 us floor at 6.3 TB/s.

constexpr int V = 32000;
constexpr int D = 8;

__global__ __launch_bounds__(256)
void ttm_kernel(const float* __restrict__ x,
                const float* __restrict__ w,
                const float* __restrict__ bias,
                float* __restrict__ out) {
    const int v4 = blockIdx.x * blockDim.x + threadIdx.x;   // group of 4 v's
    const int bt = blockIdx.y;                               // 0 .. B*T-1
    if (v4 >= V / 4) return;

    // weights: uniform-address loads, served by L1 broadcast
    const float4 w03 = *(const float4*)(w);      // w[0..3]
    const float4 w47 = *(const float4*)(w + 4);  // w[4..7]
    const float  bb  = bias[0];

    const float* xp = x + (long long)bt * (D * V) + v4 * 4;

    float4 acc;
    acc.x = bb; acc.y = bb; acc.z = bb; acc.w = bb;

    const float wd[D] = {w03.x, w03.y, w03.z, w03.w, w47.x, w47.y, w47.z, w47.w};
#pragma unroll
    for (int d = 0; d < D; ++d) {
        const float4 xv = *(const float4*)(xp + d * V);  // stride 128000 B, wave-coalesced
        acc.x += xv.x * wd[d];
        acc.y += xv.y * wd[d];
        acc.z += xv.z * wd[d];
        acc.w += xv.w * wd[d];
    }

    *(float4*)(out + (long long)bt * V + v4 * 4) = acc;
}

extern "C" void kernel_launch(void* const* d_in, const int* in_sizes, int n_in,
                              void* d_out, int out_size, void* d_ws, size_t ws_size,
                              hipStream_t stream) {
    const float* x    = (const float*)d_in[0];  // (2,512,8,32000)
    const float* w    = (const float*)d_in[1];  // (8,)
    const float* bias = (const float*)d_in[2];  // (1,)
    float* out        = (float*)d_out;          // (2,512,32000)

    const int nbt = 2 * 512;
    dim3 block(256, 1, 1);
    dim3 grid((V / 4 + 255) / 256, nbt, 1);     // (32, 1024)
    ttm_kernel<<<grid, block, 0, stream>>>(x, w, bias, out);
}